// Round 1
// baseline (174.604 us; speedup 1.0000x reference)
//
#include <hip/hip_runtime.h>
#include <cstdint>

#define N_ROWS 32768
#define KDIM 1024
#define DDIM 256

typedef __attribute__((ext_vector_type(8))) short bf16x8;
typedef __attribute__((ext_vector_type(4))) float f32x4;

__device__ __forceinline__ unsigned short f2bf(float f) {
  unsigned int u = __float_as_uint(f);
  u += 0x7FFFu + ((u >> 16) & 1u);
  return (unsigned short)(u >> 16);
}

// async global->LDS, 16B per lane. LDS dest = wave-uniform base + lane*16.
__device__ __forceinline__ void gload_lds16(const void* g, void* l) {
  __builtin_amdgcn_global_load_lds(
      (const __attribute__((address_space(1))) unsigned int*)(uintptr_t)g,
      (__attribute__((address_space(3))) unsigned int*)(unsigned int)(uintptr_t)l,
      16, 0, 0);
}

// Global layouts (u16 offsets), XOR chunk swizzle baked in (chunk = 8 u16 = 16 B):
// Cn64 [t=c>>6][kb=d>>5][c&63][32]: off = t*16384 + kb*2048 + (c&63)*32 + ((((d&31)>>3)^(c&3))*8) + (d&7)
// CnT  [s=c>>5][d][32]:            off = s*8192 + d*32 + ((((c&31)>>3)^(d&3))*8) + (c&7)
// Fragment reads use chunk = l4 ^ (l15&3) -> 2-way bank aliasing only (free).

// stage a 32-code Cn sub-tile (16 KB) out of the 64-code Cn64 layout
__device__ __forceinline__ void stage_cn32(const unsigned short* Cn, char* dstBase, int kt, int tid) {
  const int t = kt >> 1, h = kt & 1;
#pragma unroll
  for (int i = 0; i < 2; ++i) {
    const int o = i * 4096 + tid * 8;  // u16 index in [0,8192)
    const size_t g = (size_t)t * 16384 + (size_t)(o >> 10) * 2048 + (size_t)h * 1024 + (o & 1023);
    gload_lds16((const char*)(Cn + g), dstBase + (size_t)o * 2);
  }
}
// stage a 32-code CnT tile (16 KB, contiguous)
__device__ __forceinline__ void stage_cnt32(const unsigned short* CnT, char* dstBase, int kt, int tid) {
#pragma unroll
  for (int i = 0; i < 2; ++i) {
    const int o = i * 4096 + tid * 8;
    gload_lds16((const char*)(CnT + (size_t)kt * 8192 + o), dstBase + (size_t)o * 2);
  }
}

// ---------------- normalize codebook -> Cn64, CnT (bf16, swizzled)
__global__ __launch_bounds__(256) void k_norm_cb(const float* __restrict__ cb,
                                                 unsigned short* __restrict__ Cn,
                                                 unsigned short* __restrict__ CnT) {
  const int wid = threadIdx.x >> 6, lane = threadIdx.x & 63;
  const int k = blockIdx.x * 4 + wid;  // 1024 codes
  float4 v = ((const float4*)(cb + (size_t)k * DDIM))[lane];
  float s = v.x * v.x + v.y * v.y + v.z * v.z + v.w * v.w;
#pragma unroll
  for (int m = 32; m; m >>= 1) s += __shfl_xor(s, m, 64);
  const float rn = 1.0f / sqrtf(s);
  ushort4 p;
  p.x = f2bf(v.x * rn); p.y = f2bf(v.y * rn);
  p.z = f2bf(v.z * rn); p.w = f2bf(v.w * rn);
  const int kb = lane >> 3;
  const int physA = ((lane & 7) >> 1) ^ (k & 3);
  *(ushort4*)(Cn + (size_t)(k >> 6) * 16384 + kb * 2048 + (k & 63) * 32 + physA * 8 + (lane & 1) * 4) = p;
  const int sgl = k >> 5, c31 = k & 31, ch = c31 >> 3, cw = c31 & 7;
  const unsigned short pv[4] = {p.x, p.y, p.z, p.w};
#pragma unroll
  for (int j = 0; j < 4; ++j) {
    const int d = lane * 4 + j;
    CnT[(size_t)sgl * 8192 + d * 32 + ((ch ^ j) * 8) + cw] = pv[j];
  }
}

// ---------------- k_all: one block = 64 rows, 512 blocks, 2 blocks/CU.
// LDS ~74 KB: Ring 64 KB (pass A: 2x32KB Cn64 slots; pass B: CnS0/CnS1/CnTS0/CnTS1 16KB each;
// norm phase: Xs in upper 32 KB), Ps 5 KB, csl 4 KB, reductions <1 KB.
// Pass A: S-GEMM full K (K-tile 64) -> r=rowsum(exp), q=rowsum(exp^2) -> series-LSE.
// Pass B: K-tile 32: recompute S, exp->Ps, colsum (global atomics at end), PV -> out*(1/r).
__global__ __launch_bounds__(512, 4) void k_all(const float* __restrict__ x,
                                                const unsigned short* __restrict__ Cn,
                                                const unsigned short* __restrict__ CnT,
                                                float* __restrict__ colsum_g,
                                                float* __restrict__ accL,
                                                float* __restrict__ out) {
  __shared__ __align__(16) unsigned short Ring[32768];  // 64 KB
  __shared__ __align__(16) unsigned short Ps[64 * 40];  // 5 KB, stride 40 u16 (80 B, 16B-aligned)
  __shared__ float csl[1024];
  __shared__ float rs[64], qs[64], irl[64];

  const int tid = threadIdx.x, wid = tid >> 6, lane = tid & 63;
  const int l15 = lane & 15, l4 = lane >> 4;
  const int wm = wid >> 1, wn = wid & 1;  // wave: 16 rows x (32 cols S / 128 d PV)
  const int rb = blockIdx.x;              // 512 blocks x 64 rows
  if (tid < 64) { rs[tid] = 0.f; qs[tid] = 0.f; }
  for (int j = tid; j < 1024; j += 512) csl[j] = 0.f;

  // prologue: stage Cn64 tile0 -> Ring[0,32K B) while norm runs
#pragma unroll
  for (int i = 0; i < 4; ++i) {
    const int off = i * 8192 + tid * 16;
    gload_lds16((const char*)Cn + off, (char*)Ring + off);
  }

  // norm: one wave per row, 8 passes -> Xs (upper 32 KB of Ring), layout [kb8][row64][32]
  unsigned short* Xs = &Ring[16384];
#pragma unroll
  for (int p8 = 0; p8 < 8; ++p8) {
    const int row = p8 * 8 + wid;
    float4 v = ((const float4*)(x + (size_t)(rb * 64 + row) * DDIM))[lane];
    float s = v.x * v.x + v.y * v.y + v.z * v.z + v.w * v.w;
#pragma unroll
    for (int m = 32; m; m >>= 1) s += __shfl_xor(s, m, 64);
    const float rn = 1.0f / sqrtf(s);
    ushort4 p;
    p.x = f2bf(v.x * rn); p.y = f2bf(v.y * rn);
    p.z = f2bf(v.z * rn); p.w = f2bf(v.w * rn);
    *(ushort4*)&Xs[(lane >> 3) * 2048 + row * 32 + (lane & 7) * 4] = p;
  }
  __syncthreads();  // Xs visible; tile0 staged & drained
  bf16x8 areg[8];
#pragma unroll
  for (int kb = 0; kb < 8; ++kb)
    areg[kb] = *(const bf16x8*)&Xs[kb * 2048 + (wm * 16 + l15) * 32 + l4 * 8];
  __syncthreads();  // areg reads done -> upper Ring reusable as slot1

  const int xsw = l4 ^ (l15 & 3);

  // ---------------- Pass A: r, q (K-tile 64, 2-slot ring) ----------------
  float se[4] = {0.f, 0.f, 0.f, 0.f}, sq[4] = {0.f, 0.f, 0.f, 0.f};
  for (int kt = 0; kt < 16; ++kt) {
    if (kt < 15) {  // stage Cn64(kt+1) -> other slot
      const char* src = (const char*)Cn + (size_t)(kt + 1) * 32768;
      char* dst = (char*)Ring + ((kt + 1) & 1) * 32768;
#pragma unroll
      for (int i = 0; i < 4; ++i) {
        const int off = i * 8192 + tid * 16;
        gload_lds16(src + off, dst + off);
      }
    } else {
      // pre-stage pass-B Cn32 tile 0 into bytes [0,16K) (slot0 readers done at end of kt=14)
      stage_cn32(Cn, (char*)Ring, 0, tid);
    }
    const unsigned short* B = &Ring[(kt & 1) * 16384];
    f32x4 acc[2] = {};
#pragma unroll
    for (int kb = 0; kb < 8; ++kb) {
      bf16x8 b0 = *(const bf16x8*)&B[kb * 2048 + (wn * 32 + l15) * 32 + xsw * 8];
      bf16x8 b1 = *(const bf16x8*)&B[kb * 2048 + (wn * 32 + 16 + l15) * 32 + xsw * 8];
      acc[0] = __builtin_amdgcn_mfma_f32_16x16x32_bf16(areg[kb], b0, acc[0], 0, 0, 0);
      acc[1] = __builtin_amdgcn_mfma_f32_16x16x32_bf16(areg[kb], b1, acc[1], 0, 0, 0);
    }
#pragma unroll
    for (int reg = 0; reg < 4; ++reg)
#pragma unroll
      for (int ni = 0; ni < 2; ++ni) {
        const float e = __expf(acc[ni][reg]);
        se[reg] += e; sq[reg] += e * e;
      }
    __syncthreads();  // drains stage(kt+1); slot readers done
  }
  // pre-stage pass-B CnT tile 0 into bytes [32K,48K) (slot1 readers done at kt=15 barrier)
  stage_cnt32(CnT, (char*)Ring + 32768, 0, tid);

#pragma unroll
  for (int reg = 0; reg < 4; ++reg) {
#pragma unroll
    for (int m = 1; m < 16; m <<= 1) {
      se[reg] += __shfl_xor(se[reg], m, 64);
      sq[reg] += __shfl_xor(sq[reg], m, 64);
    }
  }
  if (l15 == 0) {
#pragma unroll
    for (int reg = 0; reg < 4; ++reg) {
      const int row = wm * 16 + l4 * 4 + reg;
      atomicAdd(&rs[row], se[reg]);
      atomicAdd(&qs[row], sq[reg]);
    }
  }
  __syncthreads();
  if (tid < 64) {
    const float r = rs[tid];
    const float irv = 1.0f / r;
    irl[tid] = irv;
    // series-LSE: sum_k exp(e_k/r) = K + 1 + q/(2 r^2)  (|d|~1e-3, err ~1e-9)
    float lse = logf((float)(KDIM + 1) + 0.5f * qs[tid] * irv * irv);
#pragma unroll
    for (int m = 32; m; m >>= 1) lse += __shfl_xor(lse, m, 64);
    if (tid == 0) atomicAdd(accL, lse);
  }
  __syncthreads();  // irl visible; pass-B tile0 stages drained
  float irr[4];
#pragma unroll
  for (int reg = 0; reg < 4; ++reg) irr[reg] = irl[wm * 16 + l4 * 4 + reg];

  // ---------------- Pass B: K-tile 32, recompute S, colsum, PV ----------------
  f32x4 O[8] = {};
  for (int kt = 0; kt < 32; ++kt) {
    const int cur = kt & 1;
    if (kt < 31) {  // stage(kt+1): stays in flight across the light barrier, drained at end-of-kt
      const int ns = (kt + 1) & 1;
      stage_cn32(Cn, (char*)Ring + ns * 16384, kt + 1, tid);
      stage_cnt32(CnT, (char*)Ring + 32768 + ns * 16384, kt + 1, tid);
    }
    // S on CnS[cur]
    const unsigned short* Bc = &Ring[cur * 8192];
    f32x4 S = {};
#pragma unroll
    for (int kb = 0; kb < 8; ++kb) {
      bf16x8 b = *(const bf16x8*)&Bc[kb * 1024 + (wn * 16 + l15) * 32 + xsw * 8];
      S = __builtin_amdgcn_mfma_f32_16x16x32_bf16(areg[kb], b, S, 0, 0, 0);
    }
    float cs = 0.f;
#pragma unroll
    for (int reg = 0; reg < 4; ++reg) {
      const float e = __expf(S[reg]);
      const int row = wm * 16 + l4 * 4 + reg;
      Ps[row * 40 + wn * 16 + l15] = f2bf(e);
      cs += e * irr[reg];
    }
    cs += __shfl_xor(cs, 16, 64);
    cs += __shfl_xor(cs, 32, 64);
    if (lane < 16) atomicAdd(&csl[kt * 32 + wn * 16 + l15], cs);
    // light barrier: Ps visible (lgkm only) -- leaves stage(kt+1) vmcnt in flight
    asm volatile("s_waitcnt lgkmcnt(0)" ::: "memory");
    __builtin_amdgcn_s_barrier();
    __builtin_amdgcn_sched_barrier(0);
    // PV: O += Ps @ CnT
    const unsigned short* Bt = &Ring[16384 + cur * 8192];
    bf16x8 a2 = *(const bf16x8*)&Ps[(wm * 16 + l15) * 40 + l4 * 8];
#pragma unroll
    for (int ni = 0; ni < 8; ++ni) {
      const int d = wn * 128 + ni * 16 + l15;
      bf16x8 b2 = *(const bf16x8*)&Bt[d * 32 + ((l4 ^ (d & 3)) * 8)];
      O[ni] = __builtin_amdgcn_mfma_f32_16x16x32_bf16(a2, b2, O[ni], 0, 0, 0);
    }
    __syncthreads();  // Ps reuse safe; stage(kt+1) drained
  }

  // out = O * ir
#pragma unroll
  for (int reg = 0; reg < 4; ++reg) {
    const int row = wm * 16 + l4 * 4 + reg;
    const float irv = irr[reg];
#pragma unroll
    for (int ni = 0; ni < 8; ++ni) {
      const int d = wn * 128 + ni * 16 + l15;
      out[(size_t)(rb * 64 + row) * DDIM + d] = O[ni][reg] * irv;
    }
  }
  // colsum partials -> global atomics (1024 addrs x 512 blocks; replaces the 2-MB part round-trip)
  for (int j = tid; j < 1024; j += 512) atomicAdd(&colsum_g[j], csl[j]);
}

// ---------------- final loss (k_final folded in: colsum_g is already fully reduced)
__global__ __launch_bounds__(256) void k_loss(const float* __restrict__ colsum_g,
                                              const float* __restrict__ accL,
                                              float* __restrict__ out) {
  __shared__ float sh1[4], sh2[4];
  const int tid = threadIdx.x, lane = tid & 63, w = tid >> 6;
  float s = 0.f, q = 0.f;
#pragma unroll
  for (int j = 0; j < 4; ++j) {
    const float c = colsum_g[tid + j * 256];
    s += c; q += c * c;
  }
#pragma unroll
  for (int m = 1; m < 64; m <<= 1) {
    s += __shfl_xor(s, m, 64);
    q += __shfl_xor(q, m, 64);
  }
  if (lane == 0) { sh1[w] = s; sh2[w] = q; }
  __syncthreads();
  if (tid == 0) {
    const double S = (double)sh1[0] + sh1[1] + sh1[2] + sh1[3];  // sum of all distances (~N)
    const double Q = (double)sh2[0] + sh2[1] + sh2[2] + sh2[3];  // ||colsum||^2
    const double L = accL[0];                                    // sum_i LSE_i
    const double entropy = (S * L - Q) / (double)N_ROWS;
    const double l1 = S / ((double)N_ROWS * (double)KDIM);
    out[(size_t)N_ROWS * DDIM] = (float)(1000.0 * l1 + 5e-5 * entropy);
  }
}

extern "C" void kernel_launch(void* const* d_in, const int* in_sizes, int n_in,
                              void* d_out, int out_size, void* d_ws, size_t ws_size,
                              hipStream_t stream) {
  const float* x = (const float*)d_in[0];   // [8,4096,256] fp32
  const float* cb = (const float*)d_in[1];  // [1024,256] fp32
  float* out = (float*)d_out;               // recon [8388608] + loss [1]
  char* ws = (char*)d_ws;

  unsigned short* Cn  = (unsigned short*)(ws + 0);         // 524288 B (Cn64 swizzled)
  unsigned short* CnT = (unsigned short*)(ws + 524288);    // 524288 B (CnT swizzled)
  float* colsum_g     = (float*)(ws + 1048576);            // 4096 B
  float* accL         = (float*)(ws + 1052672);            // 4 B

  hipMemsetAsync(ws + 1048576, 0, 4100, stream);
  k_norm_cb<<<256, 256, 0, stream>>>(cb, Cn, CnT);
  k_all<<<512, 512, 0, stream>>>(x, Cn, CnT, colsum_g, accL, out);
  k_loss<<<1, 256, 0, stream>>>(colsum_g, accL, out);
}